// Round 1
// baseline (628.321 us; speedup 1.0000x reference)
//
#include <hip/hip_runtime.h>

typedef unsigned short ushortT;
typedef unsigned int uintT;
typedef __attribute__((ext_vector_type(8))) short s8v;   // 8 x bf16 bits
typedef __attribute__((ext_vector_type(4))) float f4v;

#define MFMA16(a,b,c) __builtin_amdgcn_mfma_f32_16x16x32_bf16(a,b,c,0,0,0)
#define MTOT 16384

__device__ __forceinline__ ushortT f2bf(float f) {
    uintT u = __float_as_uint(f);
    u += 0x7FFFu + ((u >> 16) & 1u);   // RNE truncation to bf16
    return (ushortT)(u >> 16);
}
__device__ __forceinline__ uintT pack2(float a, float b) {
    return (uintT)f2bf(a) | ((uintT)f2bf(b) << 16);
}
__device__ __forceinline__ float elu1(float p) {
    return p > 0.f ? p + 1.f : __expf(p);
}

// K0: cast Wq,Wk to bf16 (concat layout [qk][256][256]) and zero A/qsum/ksum.
__global__ void k_prep(const float* __restrict__ wq, const float* __restrict__ wk,
                       ushortT* __restrict__ wqk, float* __restrict__ accz)
{
    int i = blockIdx.x * 256 + threadIdx.x;     // 0..65535
    wqk[i]         = f2bf(wq[i]);
    wqk[65536 + i] = f2bf(wk[i]);
    if (i < 36864) accz[i] = 0.f;               // A (32768) + qsum (2048) + ksum (2048)
}

// K1: q,k projection + elu + A/qsum/ksum accumulation.
// grid (256 m-blocks of 64, 8 batches), 256 threads (4 waves).
// wave w owns heads 4w..4w+3: q rows [w*64, w*64+64), k rows 256+[w*64, ...).
__global__ __launch_bounds__(256) void k_qk(
    const float* __restrict__ x, const ushortT* __restrict__ wqk,
    float* __restrict__ Ag, float* __restrict__ qsg, float* __restrict__ ksg)
{
    __shared__ __align__(16) ushortT w_lds[512 * 40];  // rows padded 32->40 bf16 (2-way banks, free)
    __shared__ __align__(16) ushortT x_lds[32 * 34];   // [c][m] 32x32, stride 34 (17 words, odd)
    const int t = threadIdx.x;
    const int wv = t >> 6, lane = t & 63, quad = lane >> 4, l15 = lane & 15;
    const int b = blockIdx.y;
    const int m_blk = blockIdx.x * 64;

    f4v accA[4];
    #pragma unroll
    for (int i = 0; i < 4; ++i) accA[i] = (f4v){0.f, 0.f, 0.f, 0.f};

    for (int mt = 0; mt < 2; ++mt) {
        const int mtb = m_blk + mt * 32;
        f4v aq[4][2], ak[4][2];
        #pragma unroll
        for (int i = 0; i < 4; ++i)
            #pragma unroll
            for (int j = 0; j < 2; ++j) { aq[i][j] = (f4v){0,0,0,0}; ak[i][j] = (f4v){0,0,0,0}; }

        for (int kc = 0; kc < 8; ++kc) {
            const int c0 = kc * 32;
            __syncthreads();
            // stage W chunk: 512 rows x 32 c (bf16), padded rows
            #pragma unroll
            for (int i = 0; i < 8; ++i) {
                int u = t + 256 * i;
                int row = u >> 2, qd = u & 3;
                uint4 wd = *(const uint4*)(wqk + row * 256 + c0 + qd * 8);
                *(uint4*)(&w_lds[row * 40 + qd * 8]) = wd;
            }
            // stage x chunk: [c 0..32)[m 0..32) fp32 -> bf16 pairs
            {
                int cx = t >> 3, mg = t & 7;
                const float* xp = x + ((size_t)(b * 256 + c0 + cx)) * MTOT + mtb + mg * 4;
                f4v xv = *(const f4v*)xp;
                uintT* xw = (uintT*)&x_lds[cx * 34 + mg * 4];
                xw[0] = pack2(xv.x, xv.y);
                xw[1] = pack2(xv.z, xv.w);
            }
            __syncthreads();
            // B fragments: B[k=quad*8+jj][n=l15]  (k = c index, n = m index)
            s8v bf0, bf1;
            #pragma unroll
            for (int jj = 0; jj < 8; ++jj) {
                bf0[jj] = (short)x_lds[(quad * 8 + jj) * 34 + l15];
                bf1[jj] = (short)x_lds[(quad * 8 + jj) * 34 + 16 + l15];
            }
            #pragma unroll
            for (int ot = 0; ot < 4; ++ot) {
                s8v af = *(const s8v*)(&w_lds[(wv * 64 + ot * 16 + l15) * 40 + quad * 8]);
                aq[ot][0] = MFMA16(af, bf0, aq[ot][0]);
                aq[ot][1] = MFMA16(af, bf1, aq[ot][1]);
            }
            #pragma unroll
            for (int ot = 0; ot < 4; ++ot) {
                s8v af = *(const s8v*)(&w_lds[(256 + wv * 64 + ot * 16 + l15) * 40 + quad * 8]);
                ak[ot][0] = MFMA16(af, bf0, ak[ot][0]);
                ak[ot][1] = MFMA16(af, bf1, ak[ot][1]);
            }
        }
        // epilogue: elu in place (C layout: row = ot*16 + quad*4 + r, col = j*16 + l15)
        #pragma unroll
        for (int ot = 0; ot < 4; ++ot)
            #pragma unroll
            for (int j = 0; j < 2; ++j)
                #pragma unroll
                for (int r = 0; r < 4; ++r) {
                    aq[ot][j][r] = elu1(aq[ot][j][r]);
                    ak[ot][j][r] = elu1(ak[ot][j][r]);
                }
        // qsum / ksum: reduce 16 cols across lanes, atomic per row
        #pragma unroll
        for (int ot = 0; ot < 4; ++ot)
            #pragma unroll
            for (int r = 0; r < 4; ++r) {
                float sq = aq[ot][0][r] + aq[ot][1][r];
                float sk = ak[ot][0][r] + ak[ot][1][r];
                #pragma unroll
                for (int off = 1; off < 16; off <<= 1) {
                    sq += __shfl_xor(sq, off);
                    sk += __shfl_xor(sk, off);
                }
                if (l15 == 0) {
                    atomicAdd(qsg + b * 256 + wv * 64 + ot * 16 + quad * 4 + r, sq);
                    atomicAdd(ksg + b * 256 + wv * 64 + ot * 16 + quad * 4 + r, sk);
                }
            }
        // write elu'd q,k (bf16) into the wave's OWN w_lds region (no cross-wave hazard)
        #pragma unroll
        for (int ot = 0; ot < 4; ++ot)
            #pragma unroll
            for (int j = 0; j < 2; ++j)
                #pragma unroll
                for (int r = 0; r < 4; ++r) {
                    w_lds[(wv * 64 + ot * 16 + quad * 4 + r) * 40 + j * 16 + l15] = f2bf(aq[ot][j][r]);
                    w_lds[(256 + wv * 64 + ot * 16 + quad * 4 + r) * 40 + j * 16 + l15] = f2bf(ak[ot][j][r]);
                }
        // A[d,e] += sum over this m-tile (K=32) via MFMA: A-frag = q[d][m], B-frag = k[e][m]
        #pragma unroll
        for (int ot = 0; ot < 4; ++ot) {
            s8v qa = *(const s8v*)(&w_lds[(wv * 64 + ot * 16 + l15) * 40 + quad * 8]);
            s8v kb = *(const s8v*)(&w_lds[(256 + wv * 64 + ot * 16 + l15) * 40 + quad * 8]);
            accA[ot] = MFMA16(qa, kb, accA[ot]);
        }
    }
    #pragma unroll
    for (int ot = 0; ot < 4; ++ot)
        #pragma unroll
        for (int r = 0; r < 4; ++r)
            atomicAdd(Ag + ((b * 16 + wv * 4 + ot) * 16 + quad * 4 + r) * 16 + l15, accA[ot][r]);
}

// K2: Weff[b, h*16+d, c] = z[b,d] * sum_e A[b,h,d,e] * wv[h*16+e, c]  (z of HEAD d: torch-bug replicated)
__global__ __launch_bounds__(256) void k_weff(
    const float* __restrict__ wvw, const float* __restrict__ Ag,
    const float* __restrict__ qsg, const float* __restrict__ ksg,
    ushortT* __restrict__ weff)
{
    __shared__ float A_l[256];
    __shared__ float z_l[16];
    const int t = threadIdx.x;
    const int h = blockIdx.x, b = blockIdx.y;
    A_l[t] = Ag[(b * 16 + h) * 256 + t];
    if (t < 16) {
        float s = 0.f;
        #pragma unroll
        for (int d = 0; d < 16; ++d)
            s += qsg[b * 256 + t * 16 + d] * ksg[b * 256 + t * 16 + d];
        z_l[t] = 1.f / (s + 1e-6f);
    }
    __syncthreads();
    float acc[16];
    #pragma unroll
    for (int d = 0; d < 16; ++d) acc[d] = 0.f;
    #pragma unroll 4
    for (int e = 0; e < 16; ++e) {
        float w = wvw[(h * 16 + e) * 256 + t];
        #pragma unroll
        for (int d = 0; d < 16; ++d) acc[d] += A_l[d * 16 + e] * w;
    }
    #pragma unroll
    for (int d = 0; d < 16; ++d)
        weff[((size_t)b * 256 + h * 16 + d) * 256 + t] = f2bf(acc[d] * z_l[d]);
}

// K3: out[b] = Weff[b] @ x[b]   (256x256 @ 256x16384, fp32 out)
__global__ __launch_bounds__(256) void k_out(
    const float* __restrict__ x, const ushortT* __restrict__ weff,
    float* __restrict__ out)
{
    __shared__ __align__(16) ushortT w_lds[256 * 40];
    __shared__ __align__(16) ushortT x_lds[32 * 66];   // [c][m] 32x64, stride 66 (33 words, odd)
    const int t = threadIdx.x;
    const int wv = t >> 6, lane = t & 63, quad = lane >> 4, l15 = lane & 15;
    const int b = blockIdx.y;
    const int m0 = blockIdx.x * 64;

    f4v acc[4][4];
    #pragma unroll
    for (int i = 0; i < 4; ++i)
        #pragma unroll
        for (int j = 0; j < 4; ++j) acc[i][j] = (f4v){0.f, 0.f, 0.f, 0.f};

    for (int kc = 0; kc < 8; ++kc) {
        const int c0 = kc * 32;
        __syncthreads();
        #pragma unroll
        for (int i = 0; i < 4; ++i) {
            int u = t + 256 * i;
            int row = u >> 2, qd = u & 3;
            uint4 wd = *(const uint4*)(weff + ((size_t)b * 256 + row) * 256 + c0 + qd * 8);
            *(uint4*)(&w_lds[row * 40 + qd * 8]) = wd;
        }
        #pragma unroll
        for (int i = 0; i < 2; ++i) {
            int u = t + 256 * i;
            int cx = u >> 4, mg = u & 15;
            const float* xp = x + ((size_t)(b * 256 + c0 + cx)) * MTOT + m0 + mg * 4;
            f4v xv = *(const f4v*)xp;
            uintT* xw = (uintT*)&x_lds[cx * 66 + mg * 4];
            xw[0] = pack2(xv.x, xv.y);
            xw[1] = pack2(xv.z, xv.w);
        }
        __syncthreads();
        s8v bf[4];
        #pragma unroll
        for (int j = 0; j < 4; ++j)
            #pragma unroll
            for (int jj = 0; jj < 8; ++jj)
                bf[j][jj] = (short)x_lds[(quad * 8 + jj) * 66 + j * 16 + l15];
        #pragma unroll
        for (int ot = 0; ot < 4; ++ot) {
            s8v af = *(const s8v*)(&w_lds[(wv * 64 + ot * 16 + l15) * 40 + quad * 8]);
            #pragma unroll
            for (int j = 0; j < 4; ++j)
                acc[ot][j] = MFMA16(af, bf[j], acc[ot][j]);
        }
    }
    #pragma unroll
    for (int ot = 0; ot < 4; ++ot)
        #pragma unroll
        for (int j = 0; j < 4; ++j)
            #pragma unroll
            for (int r = 0; r < 4; ++r)
                out[((size_t)b * 256 + wv * 64 + ot * 16 + quad * 4 + r) * MTOT + m0 + j * 16 + l15]
                    = acc[ot][j][r];
}

extern "C" void kernel_launch(void* const* d_in, const int* in_sizes, int n_in,
                              void* d_out, int out_size, void* d_ws, size_t ws_size,
                              hipStream_t stream)
{
    const float* x   = (const float*)d_in[0];
    const float* wq  = (const float*)d_in[1];
    const float* wk  = (const float*)d_in[2];
    const float* wvw = (const float*)d_in[3];
    float* out = (float*)d_out;
    char* ws = (char*)d_ws;
    // ws layout: wqk_bf16 [512*256] | A [8*16*16*16 f32] | qsum [8*256] | ksum [8*256] | Weff bf16 [8*256*256]
    ushortT* wqk  = (ushortT*)ws;                                  // 262144 B
    float*   Ag   = (float*)(ws + 262144);                         // 131072 B
    float*   qsg  = (float*)(ws + 262144 + 131072);                //   8192 B
    float*   ksg  = (float*)(ws + 262144 + 131072 + 8192);         //   8192 B
    ushortT* weff = (ushortT*)(ws + 262144 + 131072 + 16384);      // 1048576 B

    hipLaunchKernelGGL(k_prep, dim3(256), dim3(256), 0, stream, wq, wk, wqk, Ag);
    hipLaunchKernelGGL(k_qk,   dim3(256, 8), dim3(256), 0, stream, x, wqk, Ag, qsg, ksg);
    hipLaunchKernelGGL(k_weff, dim3(16, 8),  dim3(256), 0, stream, wvw, Ag, qsg, ksg, weff);
    hipLaunchKernelGGL(k_out,  dim3(256, 8), dim3(256), 0, stream, x, weff, out);
}

// Round 2
// 461.383 us; speedup vs baseline: 1.3618x; 1.3618x over previous
//
#include <hip/hip_runtime.h>

typedef unsigned short ushortT;
typedef unsigned int uintT;
typedef __attribute__((ext_vector_type(8))) short s8v;   // 8 x bf16 bits
typedef __attribute__((ext_vector_type(4))) float f4v;

#define MFMA16(a,b,c) __builtin_amdgcn_mfma_f32_16x16x32_bf16(a,b,c,0,0,0)
#define MTOT 16384
#define XT_STRIDE 264                     // shorts per m-row (256 data + 8 pad)
#define XT_BATCH (16384 * 264)            // shorts per batch

#define GLL(g, l, sz) __builtin_amdgcn_global_load_lds( \
    (const __attribute__((address_space(1))) void*)(g), \
    (__attribute__((address_space(3))) void*)(l), (sz), 0, 0)

__device__ __forceinline__ ushortT f2bf(float f) {
    uintT u = __float_as_uint(f);
    u += 0x7FFFu + ((u >> 16) & 1u);   // RNE truncation to bf16
    return (ushortT)(u >> 16);
}
__device__ __forceinline__ uintT pack2(float a, float b) {
    return (uintT)f2bf(a) | ((uintT)f2bf(b) << 16);
}
__device__ __forceinline__ float elu1(float p) {
    return p > 0.f ? p + 1.f : __expf(p);
}

// K0: cast Wq,Wk to bf16 (concat layout [qk][256][256]) and zero A/qsum/ksum.
__global__ void k_prep(const float* __restrict__ wq, const float* __restrict__ wk,
                       ushortT* __restrict__ wqk, float* __restrict__ accz)
{
    int i = blockIdx.x * 256 + threadIdx.x;     // 0..65535
    wqk[i]         = f2bf(wq[i]);
    wqk[65536 + i] = f2bf(wk[i]);
    if (i < 36864) accz[i] = 0.f;               // A (32768) + qsum (2048) + ksum (2048)
}

// K0b: transpose+cast x [b][c][m] fp32 -> xt [b][m][264] bf16 (64x64 tiles)
__global__ __launch_bounds__(256) void k_tx(const float* __restrict__ x,
                                            ushortT* __restrict__ xt)
{
    __shared__ ushortT tile[64 * 68];          // [c][m] pad 64->68
    const int t = threadIdx.x;
    const int m0 = blockIdx.x * 64;
    const int ct = blockIdx.y & 3, b = blockIdx.y >> 2;
    const int c0 = ct * 64;

    const int cl = t >> 4, ml = (t & 15) * 4;
    #pragma unroll
    for (int i = 0; i < 4; ++i) {
        f4v v = *(const f4v*)(x + ((size_t)(b * 256 + c0 + cl + i * 16)) * MTOT + m0 + ml);
        uintT* w = (uintT*)&tile[(cl + i * 16) * 68 + ml];
        w[0] = pack2(v.x, v.y);
        w[1] = pack2(v.z, v.w);
    }
    __syncthreads();
    const int mr = t >> 2, cc = (t & 3) * 16;
    s8v o0, o1;
    #pragma unroll
    for (int u = 0; u < 8; ++u) o0[u] = (short)tile[(cc + u) * 68 + mr];
    #pragma unroll
    for (int u = 0; u < 8; ++u) o1[u] = (short)tile[(cc + 8 + u) * 68 + mr];
    ushortT* dst = xt + (size_t)b * XT_BATCH + (size_t)(m0 + mr) * XT_STRIDE + c0 + cc;
    *(s8v*)dst = o0;
    *(s8v*)(dst + 8) = o1;
}

// K1: q,k projection + elu + A/qsum/ksum. grid (256 m-blocks of 64, 8 b), 256 thr.
// Wave wv owns q rows [wv*64, +64) and k rows 256+[wv*64, +64) = heads 4wv..4wv+3.
// W fragments read straight from global (L2-resident); x-tile staged once via
// global_load_lds; zero barriers inside the K loop.
__global__ __launch_bounds__(256, 2) void k_qk(
    const ushortT* __restrict__ xt, const ushortT* __restrict__ wqk,
    float* __restrict__ Ag, float* __restrict__ qsg, float* __restrict__ ksg)
{
    __shared__ __align__(16) ushortT lds[20480];   // x-tile 16896 sh | gram 4x(128x40) sh (union)
    const int t = threadIdx.x;
    const int wv = t >> 6, lane = t & 63, quad = lane >> 4, l15 = lane & 15;
    const int b = blockIdx.y;
    const int m0 = blockIdx.x * 64;

    // ---- stage x-tile [64 m][264 c] bf16 = 33792 B, flat copy ----
    {
        const char* gb = (const char*)(xt + (size_t)b * XT_BATCH + (size_t)m0 * XT_STRIDE);
        char* lb = (char*)lds;
        #pragma unroll
        for (int i = 0; i < 8; ++i)
            GLL(gb + i * 4096 + t * 16, lb + i * 4096 + t * 16, 16);
        GLL(gb + 32768 + t * 4, lb + 32768 + t * 4, 4);
    }
    __syncthreads();

    f4v aq[4][4], ak[4][4];
    #pragma unroll
    for (int i = 0; i < 4; ++i)
        #pragma unroll
        for (int j = 0; j < 4; ++j) { aq[i][j] = (f4v){0,0,0,0}; ak[i][j] = (f4v){0,0,0,0}; }

    const ushortT* wq_base = wqk + (wv * 64 + l15) * 256 + quad * 8;
    const ushortT* wk_base = wq_base + 65536;

    #pragma unroll 2
    for (int kc = 0; kc < 8; ++kc) {
        s8v afq[4], afk[4], bf[4];
        #pragma unroll
        for (int ot = 0; ot < 4; ++ot)
            afq[ot] = *(const s8v*)(wq_base + ot * 16 * 256 + kc * 32);
        #pragma unroll
        for (int ot = 0; ot < 4; ++ot)
            afk[ot] = *(const s8v*)(wk_base + ot * 16 * 256 + kc * 32);
        #pragma unroll
        for (int j = 0; j < 4; ++j)
            bf[j] = *(const s8v*)&lds[(j * 16 + l15) * XT_STRIDE + kc * 32 + quad * 8];
        #pragma unroll
        for (int ot = 0; ot < 4; ++ot)
            #pragma unroll
            for (int j = 0; j < 4; ++j)
                aq[ot][j] = MFMA16(afq[ot], bf[j], aq[ot][j]);
        #pragma unroll
        for (int ot = 0; ot < 4; ++ot)
            #pragma unroll
            for (int j = 0; j < 4; ++j)
                ak[ot][j] = MFMA16(afk[ot], bf[j], ak[ot][j]);
    }

    // ---- elu in place (C layout: row = ot*16+quad*4+r, m = j*16+l15) ----
    #pragma unroll
    for (int ot = 0; ot < 4; ++ot)
        #pragma unroll
        for (int j = 0; j < 4; ++j)
            #pragma unroll
            for (int r = 0; r < 4; ++r) {
                aq[ot][j][r] = elu1(aq[ot][j][r]);
                ak[ot][j][r] = elu1(ak[ot][j][r]);
            }

    // ---- qsum/ksum ----
    #pragma unroll
    for (int ot = 0; ot < 4; ++ot)
        #pragma unroll
        for (int r = 0; r < 4; ++r) {
            float sq = aq[ot][0][r] + aq[ot][1][r] + aq[ot][2][r] + aq[ot][3][r];
            float sk = ak[ot][0][r] + ak[ot][1][r] + ak[ot][2][r] + ak[ot][3][r];
            #pragma unroll
            for (int off = 1; off < 16; off <<= 1) {
                sq += __shfl_xor(sq, off);
                sk += __shfl_xor(sk, off);
            }
            if (l15 == 0) {
                atomicAdd(qsg + b * 256 + wv * 64 + ot * 16 + quad * 4 + r, sq);
                atomicAdd(ksg + b * 256 + wv * 64 + ot * 16 + quad * 4 + r, sk);
            }
        }

    // ---- Gram A[d,e] via MFMA, per-wave LDS region (reuses x region) ----
    __syncthreads();   // all waves done reading x-tile
    f4v accA[4];
    #pragma unroll
    for (int i = 0; i < 4; ++i) accA[i] = (f4v){0,0,0,0};
    const int GB = wv * 5120;   // per-wave region: 128 rows x 40 shorts
    #pragma unroll
    for (int hf = 0; hf < 2; ++hf) {
        #pragma unroll
        for (int ot = 0; ot < 4; ++ot)
            #pragma unroll
            for (int jj = 0; jj < 2; ++jj)
                #pragma unroll
                for (int r = 0; r < 4; ++r) {
                    int row = ot * 16 + quad * 4 + r;
                    lds[GB + row * 40 + jj * 16 + l15]        = f2bf(aq[ot][hf * 2 + jj][r]);
                    lds[GB + (64 + row) * 40 + jj * 16 + l15] = f2bf(ak[ot][hf * 2 + jj][r]);
                }
        #pragma unroll
        for (int ot = 0; ot < 4; ++ot) {
            s8v qa = *(const s8v*)&lds[GB + (ot * 16 + l15) * 40 + quad * 8];
            s8v kb = *(const s8v*)&lds[GB + (64 + ot * 16 + l15) * 40 + quad * 8];
            accA[ot] = MFMA16(qa, kb, accA[ot]);
        }
    }
    #pragma unroll
    for (int ot = 0; ot < 4; ++ot)
        #pragma unroll
        for (int r = 0; r < 4; ++r)
            atomicAdd(Ag + ((b * 16 + wv * 4 + ot) * 16 + quad * 4 + r) * 16 + l15, accA[ot][r]);
}

// K2: Weff[b, h*16+d, c] = z[b,d] * sum_e A[b,h,d,e] * wv[h*16+e, c]  (z of HEAD d)
__global__ __launch_bounds__(256) void k_weff(
    const float* __restrict__ wvw, const float* __restrict__ Ag,
    const float* __restrict__ qsg, const float* __restrict__ ksg,
    ushortT* __restrict__ weff)
{
    __shared__ float A_l[256];
    __shared__ float z_l[16];
    const int t = threadIdx.x;
    const int h = blockIdx.x, b = blockIdx.y;
    A_l[t] = Ag[(b * 16 + h) * 256 + t];
    if (t < 16) {
        float s = 0.f;
        #pragma unroll
        for (int d = 0; d < 16; ++d)
            s += qsg[b * 256 + t * 16 + d] * ksg[b * 256 + t * 16 + d];
        z_l[t] = 1.f / (s + 1e-6f);
    }
    __syncthreads();
    float acc[16];
    #pragma unroll
    for (int d = 0; d < 16; ++d) acc[d] = 0.f;
    #pragma unroll 4
    for (int e = 0; e < 16; ++e) {
        float w = wvw[(h * 16 + e) * 256 + t];
        #pragma unroll
        for (int d = 0; d < 16; ++d) acc[d] += A_l[d * 16 + e] * w;
    }
    #pragma unroll
    for (int d = 0; d < 16; ++d)
        weff[((size_t)b * 256 + h * 16 + d) * 256 + t] = f2bf(acc[d] * z_l[d]);
}

// K3: out[b] = Weff[b] @ x[b]  (256x256 @ 256x16384, fp32 out). Same structure as k_qk.
__global__ __launch_bounds__(256, 4) void k_out(
    const ushortT* __restrict__ xt, const ushortT* __restrict__ weff,
    float* __restrict__ out)
{
    __shared__ __align__(16) ushortT lds[16896];   // x-tile [64 m][264 c]
    const int t = threadIdx.x;
    const int wv = t >> 6, lane = t & 63, quad = lane >> 4, l15 = lane & 15;
    const int b = blockIdx.y;
    const int m0 = blockIdx.x * 64;

    {
        const char* gb = (const char*)(xt + (size_t)b * XT_BATCH + (size_t)m0 * XT_STRIDE);
        char* lb = (char*)lds;
        #pragma unroll
        for (int i = 0; i < 8; ++i)
            GLL(gb + i * 4096 + t * 16, lb + i * 4096 + t * 16, 16);
        GLL(gb + 32768 + t * 4, lb + 32768 + t * 4, 4);
    }
    __syncthreads();

    f4v acc[4][4];
    #pragma unroll
    for (int i = 0; i < 4; ++i)
        #pragma unroll
        for (int j = 0; j < 4; ++j) acc[i][j] = (f4v){0,0,0,0};

    const ushortT* w_base = weff + (size_t)b * 65536 + (wv * 64 + l15) * 256 + quad * 8;

    #pragma unroll 2
    for (int kc = 0; kc < 8; ++kc) {
        s8v af[4], bf[4];
        #pragma unroll
        for (int ot = 0; ot < 4; ++ot)
            af[ot] = *(const s8v*)(w_base + ot * 16 * 256 + kc * 32);
        #pragma unroll
        for (int j = 0; j < 4; ++j)
            bf[j] = *(const s8v*)&lds[(j * 16 + l15) * XT_STRIDE + kc * 32 + quad * 8];
        #pragma unroll
        for (int ot = 0; ot < 4; ++ot)
            #pragma unroll
            for (int j = 0; j < 4; ++j)
                acc[ot][j] = MFMA16(af[ot], bf[j], acc[ot][j]);
    }

    #pragma unroll
    for (int ot = 0; ot < 4; ++ot)
        #pragma unroll
        for (int j = 0; j < 4; ++j)
            #pragma unroll
            for (int r = 0; r < 4; ++r)
                out[((size_t)b * 256 + wv * 64 + ot * 16 + quad * 4 + r) * MTOT + m0 + j * 16 + l15]
                    = acc[ot][j][r];
}

extern "C" void kernel_launch(void* const* d_in, const int* in_sizes, int n_in,
                              void* d_out, int out_size, void* d_ws, size_t ws_size,
                              hipStream_t stream)
{
    const float* x   = (const float*)d_in[0];
    const float* wq  = (const float*)d_in[1];
    const float* wk  = (const float*)d_in[2];
    const float* wvw = (const float*)d_in[3];
    float* out = (float*)d_out;
    char* ws = (char*)d_ws;
    // ws layout: wqk bf16 262144 | Ag 131072 | qsg 8192 | ksg 8192 | weff 1048576 | xt 69206016
    ushortT* wqk  = (ushortT*)ws;
    float*   Ag   = (float*)(ws + 262144);
    float*   qsg  = (float*)(ws + 393216);
    float*   ksg  = (float*)(ws + 401408);
    ushortT* weff = (ushortT*)(ws + 409600);
    ushortT* xt   = (ushortT*)(ws + 1458176);   // 16B aligned; needs 69206016 B

    hipLaunchKernelGGL(k_prep, dim3(256), dim3(256), 0, stream, wq, wk, wqk, Ag);
    hipLaunchKernelGGL(k_tx,   dim3(256, 32), dim3(256), 0, stream, x, xt);
    hipLaunchKernelGGL(k_qk,   dim3(256, 8), dim3(256), 0, stream, xt, wqk, Ag, qsg, ksg);
    hipLaunchKernelGGL(k_weff, dim3(16, 8),  dim3(256), 0, stream, wvw, Ag, qsg, ksg, weff);
    hipLaunchKernelGGL(k_out,  dim3(256, 8), dim3(256), 0, stream, xt, weff, out);
}

// Round 3
// 386.181 us; speedup vs baseline: 1.6270x; 1.1947x over previous
//
#include <hip/hip_runtime.h>

typedef unsigned short ushortT;
typedef unsigned int uintT;
typedef __attribute__((ext_vector_type(8))) short s8v;   // 8 x bf16 bits
typedef __attribute__((ext_vector_type(4))) float f4v;

#define MFMA16(a,b,c) __builtin_amdgcn_mfma_f32_16x16x32_bf16(a,b,c,0,0,0)
#define MTOT 16384
#define XT_STRIDE 264                     // shorts per m-row (256 data + 8 pad)
#define XT_BATCH (16384 * 264)            // shorts per batch
#define XBUF_SH 16896                     // shorts per x-tile buffer (64*264)
#define XBUF_B  33792                     // bytes per x-tile buffer

#define GLL(g, l, sz) __builtin_amdgcn_global_load_lds( \
    (const __attribute__((address_space(1))) void*)(g), \
    (__attribute__((address_space(3))) void*)(l), (sz), 0, 0)

__device__ __forceinline__ ushortT f2bf(float f) {
    uintT u = __float_as_uint(f);
    u += 0x7FFFu + ((u >> 16) & 1u);   // RNE truncation to bf16
    return (ushortT)(u >> 16);
}
__device__ __forceinline__ uintT pack2(float a, float b) {
    return (uintT)f2bf(a) | ((uintT)f2bf(b) << 16);
}
__device__ __forceinline__ float elu1(float p) {
    return p > 0.f ? p + 1.f : __expf(p);
}

// K0: cast Wq,Wk to bf16 (concat layout [qk][256][256]) and zero A/qsum/ksum.
__global__ void k_prep(const float* __restrict__ wq, const float* __restrict__ wk,
                       ushortT* __restrict__ wqk, float* __restrict__ accz)
{
    int i = blockIdx.x * 256 + threadIdx.x;     // 0..65535
    wqk[i]         = f2bf(wq[i]);
    wqk[65536 + i] = f2bf(wk[i]);
    if (i < 36864) accz[i] = 0.f;               // A (32768) + qsum (2048) + ksum (2048)
}

// K0b: transpose+cast x [b][c][m] fp32 -> xt [b][m][264] bf16 (64x64 tiles)
__global__ __launch_bounds__(256) void k_tx(const float* __restrict__ x,
                                            ushortT* __restrict__ xt)
{
    __shared__ ushortT tile[64 * 68];          // [c][m] pad 64->68
    const int t = threadIdx.x;
    const int m0 = blockIdx.x * 64;
    const int ct = blockIdx.y & 3, b = blockIdx.y >> 2;
    const int c0 = ct * 64;

    const int cl = t >> 4, ml = (t & 15) * 4;
    #pragma unroll
    for (int i = 0; i < 4; ++i) {
        f4v v = *(const f4v*)(x + ((size_t)(b * 256 + c0 + cl + i * 16)) * MTOT + m0 + ml);
        uintT* w = (uintT*)&tile[(cl + i * 16) * 68 + ml];
        w[0] = pack2(v.x, v.y);
        w[1] = pack2(v.z, v.w);
    }
    __syncthreads();
    const int mr = t >> 2, cc = (t & 3) * 16;
    s8v o0, o1;
    #pragma unroll
    for (int u = 0; u < 8; ++u) o0[u] = (short)tile[(cc + u) * 68 + mr];
    #pragma unroll
    for (int u = 0; u < 8; ++u) o1[u] = (short)tile[(cc + 8 + u) * 68 + mr];
    ushortT* dst = xt + (size_t)b * XT_BATCH + (size_t)(m0 + mr) * XT_STRIDE + c0 + cc;
    *(s8v*)dst = o0;
    *(s8v*)(dst + 8) = o1;
}

// K1: q,k projection + elu + A/qsum/ksum. grid (64, 8): 4 m-tiles of 64 per block.
// Double-buffered GLL staging of x-tiles; weights from global (L2); Gram via
// per-wave private LDS region (no extra barriers). One barrier per tile.
__global__ __launch_bounds__(256, 2) void k_qk(
    const ushortT* __restrict__ xt, const ushortT* __restrict__ wqk,
    float* __restrict__ Ag, float* __restrict__ qsg, float* __restrict__ ksg)
{
    __shared__ __align__(16) ushortT lds[2 * XBUF_SH + 4 * 1280]; // 77824 B
    const int t = threadIdx.x;
    const int wv = t >> 6, lane = t & 63, quad = lane >> 4, l15 = lane & 15;
    const int b = blockIdx.y;
    const size_t xtb = (size_t)b * XT_BATCH + (size_t)(blockIdx.x * 256) * XT_STRIDE;

    ushortT* gram = lds + 2 * XBUF_SH + wv * 1280;   // 32 rows x 40 shorts, per-wave
    float* gramf = (float*)gram;

    f4v accA[4];
    float qacc[4][4], kacc[4][4];
    #pragma unroll
    for (int i = 0; i < 4; ++i) {
        accA[i] = (f4v){0,0,0,0};
        #pragma unroll
        for (int r = 0; r < 4; ++r) { qacc[i][r] = 0.f; kacc[i][r] = 0.f; }
    }

    const ushortT* wq_base = wqk + (wv * 64 + l15) * 256 + quad * 8;
    const ushortT* wk_base = wq_base + 65536;

    // stage tile 0 -> buf 0
    {
        const char* gb = (const char*)(xt + xtb);
        char* lb = (char*)lds;
        #pragma unroll
        for (int i = 0; i < 8; ++i) GLL(gb + i * 4096 + t * 16, lb + i * 4096 + t * 16, 16);
        GLL(gb + 32768 + t * 4, lb + 32768 + t * 4, 4);
    }

    for (int tt = 0; tt < 4; ++tt) {
        __syncthreads();                           // buf[tt&1] ready; all waves past tile tt-1
        if (tt < 3) {                              // prefetch tile tt+1 -> other buf
            const char* gb = (const char*)(xt + xtb) + (size_t)(tt + 1) * (64 * XT_STRIDE * 2);
            char* lb = (char*)lds + ((tt + 1) & 1) * XBUF_B;
            #pragma unroll
            for (int i = 0; i < 8; ++i) GLL(gb + i * 4096 + t * 16, lb + i * 4096 + t * 16, 16);
            GLL(gb + 32768 + t * 4, lb + 32768 + t * 4, 4);
        }
        const ushortT* xb = lds + (tt & 1) * XBUF_SH;

        f4v aq[4][4], ak[4][4];
        #pragma unroll
        for (int i = 0; i < 4; ++i)
            #pragma unroll
            for (int j = 0; j < 4; ++j) { aq[i][j] = (f4v){0,0,0,0}; ak[i][j] = (f4v){0,0,0,0}; }

        #pragma unroll 2
        for (int kc = 0; kc < 8; ++kc) {
            s8v afq[4], afk[4], bf[4];
            #pragma unroll
            for (int ot = 0; ot < 4; ++ot)
                afq[ot] = *(const s8v*)(wq_base + ot * 16 * 256 + kc * 32);
            #pragma unroll
            for (int ot = 0; ot < 4; ++ot)
                afk[ot] = *(const s8v*)(wk_base + ot * 16 * 256 + kc * 32);
            #pragma unroll
            for (int j = 0; j < 4; ++j)
                bf[j] = *(const s8v*)&xb[(j * 16 + l15) * XT_STRIDE + kc * 32 + quad * 8];
            #pragma unroll
            for (int ot = 0; ot < 4; ++ot)
                #pragma unroll
                for (int j = 0; j < 4; ++j)
                    aq[ot][j] = MFMA16(afq[ot], bf[j], aq[ot][j]);
            #pragma unroll
            for (int ot = 0; ot < 4; ++ot)
                #pragma unroll
                for (int j = 0; j < 4; ++j)
                    ak[ot][j] = MFMA16(afk[ot], bf[j], ak[ot][j]);
        }

        // elu in place (C layout: row = ot*16+quad*4+r, m = j*16+l15)
        #pragma unroll
        for (int ot = 0; ot < 4; ++ot)
            #pragma unroll
            for (int j = 0; j < 4; ++j)
                #pragma unroll
                for (int r = 0; r < 4; ++r) {
                    aq[ot][j][r] = elu1(aq[ot][j][r]);
                    ak[ot][j][r] = elu1(ak[ot][j][r]);
                }

        // qsum/ksum: butterfly over l15 -> every lane holds the row sum; accumulate in regs
        #pragma unroll
        for (int ot = 0; ot < 4; ++ot)
            #pragma unroll
            for (int r = 0; r < 4; ++r) {
                float sq = aq[ot][0][r] + aq[ot][1][r] + aq[ot][2][r] + aq[ot][3][r];
                float sk = ak[ot][0][r] + ak[ot][1][r] + ak[ot][2][r] + ak[ot][3][r];
                #pragma unroll
                for (int off = 1; off < 16; off <<= 1) {
                    sq += __shfl_xor(sq, off);
                    sk += __shfl_xor(sk, off);
                }
                qacc[ot][r] += sq;
                kacc[ot][r] += sk;
            }

        // Gram per (hf, ot): q rows 0..15, k rows 16..31 of the per-wave region
        #pragma unroll
        for (int hf = 0; hf < 2; ++hf)
            #pragma unroll
            for (int ot = 0; ot < 4; ++ot) {
                #pragma unroll
                for (int jj = 0; jj < 2; ++jj)
                    #pragma unroll
                    for (int r = 0; r < 4; ++r) {
                        int d = quad * 4 + r;
                        gram[d * 40 + jj * 16 + l15]        = f2bf(aq[ot][hf * 2 + jj][r]);
                        gram[(16 + d) * 40 + jj * 16 + l15] = f2bf(ak[ot][hf * 2 + jj][r]);
                    }
                s8v qa = *(const s8v*)&gram[l15 * 40 + quad * 8];
                s8v kb = *(const s8v*)&gram[(16 + l15) * 40 + quad * 8];
                accA[ot] = MFMA16(qa, kb, accA[ot]);
            }
    }

    // final: Ag atomics (full 64B lines)
    #pragma unroll
    for (int ot = 0; ot < 4; ++ot)
        #pragma unroll
        for (int r = 0; r < 4; ++r)
            atomicAdd(Ag + ((b * 16 + wv * 4 + ot) * 16 + quad * 4 + r) * 16 + l15, accA[ot][r]);

    // final: qsum/ksum via gram region -> one coalesced 64-lane atomic each
    if (l15 == 0) {
        #pragma unroll
        for (int ot = 0; ot < 4; ++ot)
            #pragma unroll
            for (int r = 0; r < 4; ++r) {
                int row = ot * 16 + quad * 4 + r;
                gramf[row]      = qacc[ot][r];
                gramf[64 + row] = kacc[ot][r];
            }
    }
    float myq = gramf[lane];
    float myk = gramf[64 + lane];
    atomicAdd(qsg + b * 256 + wv * 64 + lane, myq);
    atomicAdd(ksg + b * 256 + wv * 64 + lane, myk);
}

// K2: Weff[b, h*16+d, c] = z[b,d] * sum_e A[b,h,d,e] * wv[h*16+e, c]  (z of HEAD d)
__global__ __launch_bounds__(256) void k_weff(
    const float* __restrict__ wvw, const float* __restrict__ Ag,
    const float* __restrict__ qsg, const float* __restrict__ ksg,
    ushortT* __restrict__ weff)
{
    __shared__ float A_l[256];
    __shared__ float z_l[16];
    const int t = threadIdx.x;
    const int h = blockIdx.x, b = blockIdx.y;
    A_l[t] = Ag[(b * 16 + h) * 256 + t];
    if (t < 16) {
        float s = 0.f;
        #pragma unroll
        for (int d = 0; d < 16; ++d)
            s += qsg[b * 256 + t * 16 + d] * ksg[b * 256 + t * 16 + d];
        z_l[t] = 1.f / (s + 1e-6f);
    }
    __syncthreads();
    float acc[16];
    #pragma unroll
    for (int d = 0; d < 16; ++d) acc[d] = 0.f;
    #pragma unroll 4
    for (int e = 0; e < 16; ++e) {
        float w = wvw[(h * 16 + e) * 256 + t];
        #pragma unroll
        for (int d = 0; d < 16; ++d) acc[d] += A_l[d * 16 + e] * w;
    }
    #pragma unroll
    for (int d = 0; d < 16; ++d)
        weff[((size_t)b * 256 + h * 16 + d) * 256 + t] = f2bf(acc[d] * z_l[d]);
}

// K3: out[b] = Weff[b] @ x[b]. grid (64, 8): 4 m-tiles per block, double-buffered.
__global__ __launch_bounds__(256, 2) void k_out(
    const ushortT* __restrict__ xt, const ushortT* __restrict__ weff,
    float* __restrict__ out)
{
    __shared__ __align__(16) ushortT lds[2 * XBUF_SH];   // 67584 B
    const int t = threadIdx.x;
    const int wv = t >> 6, lane = t & 63, quad = lane >> 4, l15 = lane & 15;
    const int b = blockIdx.y;
    const size_t xtb = (size_t)b * XT_BATCH + (size_t)(blockIdx.x * 256) * XT_STRIDE;

    const ushortT* w_base = weff + (size_t)b * 65536 + (wv * 64 + l15) * 256 + quad * 8;

    {
        const char* gb = (const char*)(xt + xtb);
        char* lb = (char*)lds;
        #pragma unroll
        for (int i = 0; i < 8; ++i) GLL(gb + i * 4096 + t * 16, lb + i * 4096 + t * 16, 16);
        GLL(gb + 32768 + t * 4, lb + 32768 + t * 4, 4);
    }

    for (int tt = 0; tt < 4; ++tt) {
        __syncthreads();
        if (tt < 3) {
            const char* gb = (const char*)(xt + xtb) + (size_t)(tt + 1) * (64 * XT_STRIDE * 2);
            char* lb = (char*)lds + ((tt + 1) & 1) * XBUF_B;
            #pragma unroll
            for (int i = 0; i < 8; ++i) GLL(gb + i * 4096 + t * 16, lb + i * 4096 + t * 16, 16);
            GLL(gb + 32768 + t * 4, lb + 32768 + t * 4, 4);
        }
        const ushortT* xb = lds + (tt & 1) * XBUF_SH;

        f4v acc[4][4];
        #pragma unroll
        for (int i = 0; i < 4; ++i)
            #pragma unroll
            for (int j = 0; j < 4; ++j) acc[i][j] = (f4v){0,0,0,0};

        #pragma unroll 2
        for (int kc = 0; kc < 8; ++kc) {
            s8v af[4], bf[4];
            #pragma unroll
            for (int ot = 0; ot < 4; ++ot)
                af[ot] = *(const s8v*)(w_base + ot * 16 * 256 + kc * 32);
            #pragma unroll
            for (int j = 0; j < 4; ++j)
                bf[j] = *(const s8v*)&xb[(j * 16 + l15) * XT_STRIDE + kc * 32 + quad * 8];
            #pragma unroll
            for (int ot = 0; ot < 4; ++ot)
                #pragma unroll
                for (int j = 0; j < 4; ++j)
                    acc[ot][j] = MFMA16(af[ot], bf[j], acc[ot][j]);
        }

        const int m0 = (blockIdx.x * 4 + tt) * 64;
        #pragma unroll
        for (int ot = 0; ot < 4; ++ot)
            #pragma unroll
            for (int j = 0; j < 4; ++j)
                #pragma unroll
                for (int r = 0; r < 4; ++r)
                    out[((size_t)b * 256 + wv * 64 + ot * 16 + quad * 4 + r) * MTOT
                        + m0 + j * 16 + l15] = acc[ot][j][r];
    }
}

extern "C" void kernel_launch(void* const* d_in, const int* in_sizes, int n_in,
                              void* d_out, int out_size, void* d_ws, size_t ws_size,
                              hipStream_t stream)
{
    const float* x   = (const float*)d_in[0];
    const float* wq  = (const float*)d_in[1];
    const float* wk  = (const float*)d_in[2];
    const float* wvw = (const float*)d_in[3];
    float* out = (float*)d_out;
    char* ws = (char*)d_ws;
    // ws layout: wqk bf16 262144 | Ag 131072 | qsg 8192 | ksg 8192 | weff 1048576 | xt 69206016
    ushortT* wqk  = (ushortT*)ws;
    float*   Ag   = (float*)(ws + 262144);
    float*   qsg  = (float*)(ws + 393216);
    float*   ksg  = (float*)(ws + 401408);
    ushortT* weff = (ushortT*)(ws + 409600);
    ushortT* xt   = (ushortT*)(ws + 1458176);

    hipLaunchKernelGGL(k_prep, dim3(256), dim3(256), 0, stream, wq, wk, wqk, Ag);
    hipLaunchKernelGGL(k_tx,   dim3(256, 32), dim3(256), 0, stream, x, xt);
    hipLaunchKernelGGL(k_qk,   dim3(64, 8), dim3(256), 0, stream, xt, wqk, Ag, qsg, ksg);
    hipLaunchKernelGGL(k_weff, dim3(16, 8),  dim3(256), 0, stream, wvw, Ag, qsg, ksg, weff);
    hipLaunchKernelGGL(k_out,  dim3(64, 8), dim3(256), 0, stream, xt, weff, out);
}